// Round 5
// baseline (10566.463 us; speedup 1.0000x reference)
//
#include <hip/hip_runtime.h>

#define N_NODES 200000
#define N_EDGES 6400000
#define EMB 16
#define CONT 12
#define H 128
#define IN_DIM 60   // 3*EMB + CONT
#define NPB 32      // nodes per block for dense kernels (200000 % 32 == 0)
#define TPB 256

#define BROWS 128                                        // rows per bucket
#define NBUCK ((N_NODES + BROWS - 1) / BROWS)            // 1563
#define SORT_TILE 16384
#define SORT_TPB 512
#define N_SORT_BLOCKS ((N_EDGES + SORT_TILE - 1) / SORT_TILE)  // 391
#define SPMM_TPB 512

// bf16 round-to-nearest-even pack helper (h >= 0, finite; no NaN concern)
__device__ __forceinline__ unsigned bf_rne(float f) {
    unsigned u = __float_as_uint(f);
    return (u + 0x7FFFu + ((u >> 16) & 1u)) >> 16;
}

// ---------------------------------------------------------------------------
// K1: fused embedding gather + 2-layer input MLP + optional bf16 pack.
// 4x4 register blocking (see round-4 notes): FMA-bound, LDS broadcast reads.
// ---------------------------------------------------------------------------
__global__ __launch_bounds__(TPB) void k_input_mlp(
    const int* __restrict__ midx, const int* __restrict__ widx,
    const int* __restrict__ tidx, const float* __restrict__ cont,
    const float* __restrict__ memb, const float* __restrict__ wemb,
    const float* __restrict__ temb,
    const float* __restrict__ W1, const float* __restrict__ b1,
    const float* __restrict__ W2, const float* __restrict__ b2,
    float* __restrict__ h, unsigned* __restrict__ hb)
{
    __shared__ float x_lds[NPB][IN_DIM];
    __shared__ float h0_lds[NPB][H];
    const int tid  = threadIdx.x;
    const int base = blockIdx.x * NPB;

    for (int idx = tid; idx < NPB * IN_DIM; idx += TPB) {
        int n = idx / IN_DIM, k = idx % IN_DIM;
        int node = base + n;
        float v;
        if (k < 16)       v = memb[midx[node] * 16 + k];
        else if (k < 32)  v = wemb[widx[node] * 16 + (k - 16)];
        else if (k < 48)  v = temb[tidx[node] * 16 + (k - 32)];
        else              v = cont[(size_t)node * CONT + (k - 48)];
        x_lds[n][k] = v;
    }
    __syncthreads();

    const int c0 = (tid & 31) * 4;
    const int r0 = (tid >> 5) * 4;

    float acc[4][4];
    #pragma unroll
    for (int i = 0; i < 4; i++)
        #pragma unroll
        for (int j = 0; j < 4; j++) acc[i][j] = 0.f;

    for (int k = 0; k < IN_DIM; k += 4) {
        float4 a[4];
        #pragma unroll
        for (int i = 0; i < 4; i++) a[i] = *(const float4*)&x_lds[r0 + i][k];
        #pragma unroll
        for (int kk = 0; kk < 4; kk++) {
            float4 w = *(const float4*)(W1 + (size_t)(k + kk) * H + c0);
            const float* wf = (const float*)&w;
            #pragma unroll
            for (int i = 0; i < 4; i++) {
                float av = ((const float*)&a[i])[kk];
                #pragma unroll
                for (int j = 0; j < 4; j++)
                    acc[i][j] += av * wf[j];
            }
        }
    }
    {
        float4 bv = *(const float4*)(b1 + c0);
        const float* bf = (const float*)&bv;
        #pragma unroll
        for (int i = 0; i < 4; i++)
            #pragma unroll
            for (int j = 0; j < 4; j++)
                h0_lds[r0 + i][c0 + j] = fmaxf(acc[i][j] + bf[j], 0.f);
    }
    __syncthreads();

    #pragma unroll
    for (int i = 0; i < 4; i++)
        #pragma unroll
        for (int j = 0; j < 4; j++) acc[i][j] = 0.f;

    for (int k = 0; k < H; k += 4) {
        float4 a[4];
        #pragma unroll
        for (int i = 0; i < 4; i++) a[i] = *(const float4*)&h0_lds[r0 + i][k];
        #pragma unroll
        for (int kk = 0; kk < 4; kk++) {
            float4 w = *(const float4*)(W2 + (size_t)(k + kk) * H + c0);
            const float* wf = (const float*)&w;
            #pragma unroll
            for (int i = 0; i < 4; i++) {
                float av = ((const float*)&a[i])[kk];
                #pragma unroll
                for (int j = 0; j < 4; j++)
                    acc[i][j] += av * wf[j];
            }
        }
    }
    {
        float4 bv = *(const float4*)(b2 + c0);
        const float* bf = (const float*)&bv;
        #pragma unroll
        for (int i = 0; i < 4; i++) {
            int node = base + r0 + i;
            float4 out;
            float* of = (float*)&out;
            #pragma unroll
            for (int j = 0; j < 4; j++)
                of[j] = fmaxf(acc[i][j] + bf[j], 0.f);
            *(float4*)(h + (size_t)node * H + c0) = out;
            if (hb) {
                uint2 p;
                p.x = bf_rne(of[0]) | (bf_rne(of[1]) << 16);
                p.y = bf_rne(of[2]) | (bf_rne(of[3]) << 16);
                *(uint2*)(hb + (size_t)node * 64 + (c0 >> 1)) = p;
            }
        }
    }
}

// ---------------------------------------------------------------------------
// Bucket build: global bucket histogram -> scan -> tiled bucket scatter.
// Bucket b covers rows [b*128, b*128+128). Each sort tile reserves contiguous
// per-bucket segments so writes of a segment come from one block (one XCD):
// the L2 write-combines lines instead of 64-B-per-8-B amplification.
// ---------------------------------------------------------------------------
__global__ __launch_bounds__(256) void k_bucket_hist(
    const int* __restrict__ erow, int* __restrict__ bhist)
{
    __shared__ int lh[NBUCK];
    for (int i = threadIdx.x; i < NBUCK; i += 256) lh[i] = 0;
    __syncthreads();
    for (int e = blockIdx.x * 256 + threadIdx.x; e < N_EDGES; e += gridDim.x * 256)
        atomicAdd(&lh[erow[e] >> 7], 1);
    __syncthreads();
    for (int i = threadIdx.x; i < NBUCK; i += 256) {
        int v = lh[i];
        if (v) atomicAdd(&bhist[i], v);
    }
}

__global__ __launch_bounds__(1024) void k_scan_buckets(
    const int* __restrict__ bhist, int* __restrict__ bucket_off,
    int* __restrict__ bucket_cur)
{
    __shared__ int s[1024];
    int t = threadIdx.x;
    int i0 = t * 2, i1 = t * 2 + 1;
    int v0 = (i0 < NBUCK) ? bhist[i0] : 0;
    int v1 = (i1 < NBUCK) ? bhist[i1] : 0;
    s[t] = v0 + v1;
    __syncthreads();
    for (int off = 1; off < 1024; off <<= 1) {
        int u = (t >= off) ? s[t - off] : 0;
        __syncthreads();
        s[t] += u;
        __syncthreads();
    }
    int base = (t > 0) ? s[t - 1] : 0;
    if (i0 < NBUCK) { bucket_off[i0] = base;      bucket_cur[i0] = base; }
    if (i1 < NBUCK) { bucket_off[i1] = base + v0; bucket_cur[i1] = base + v0; }
    if (t == 1023) bucket_off[NBUCK] = s[1023];   // == N_EDGES
}

__global__ __launch_bounds__(SORT_TPB) void k_bucket_sort(
    const int* __restrict__ erow, const int* __restrict__ ecol,
    const float* __restrict__ eval, int* __restrict__ bucket_cur,
    long long* __restrict__ bkt)
{
    __shared__ int hist[NBUCK];
    __shared__ int gbase[NBUCK];
    __shared__ int fcur[NBUCK];
    const int t = threadIdx.x;
    const int tile0 = blockIdx.x * SORT_TILE;
    const int nE = min(SORT_TILE, N_EDGES - tile0);

    for (int i = t; i < NBUCK; i += SORT_TPB) { hist[i] = 0; fcur[i] = 0; }
    __syncthreads();
    for (int i = t; i < nE; i += SORT_TPB)
        atomicAdd(&hist[erow[tile0 + i] >> 7], 1);
    __syncthreads();
    for (int i = t; i < NBUCK; i += SORT_TPB) {
        int c = hist[i];
        if (c) gbase[i] = atomicAdd(&bucket_cur[i], c);
    }
    __syncthreads();
    for (int i = t; i < nE; i += SORT_TPB) {
        int r = erow[tile0 + i];
        int b = r >> 7;
        int off = atomicAdd(&fcur[b], 1);
        unsigned w0 = (unsigned)ecol[tile0 + i] | ((unsigned)(r & 127) << 24);
        unsigned w1 = (unsigned)__float_as_int(eval[tile0 + i]);
        bkt[gbase[b] + off] = (long long)(((unsigned long long)w1 << 32) | w0);
    }
}

// ---------------------------------------------------------------------------
// K2: bucket SpMM — one block per bucket, 128x128 fp32 accumulator in LDS,
// ds_add_f32 accumulation (no global atomics), coalesced 256-B row gathers.
// ---------------------------------------------------------------------------
__global__ __launch_bounds__(SPMM_TPB, 1) void k_spmm_bucket_bf16(
    const int* __restrict__ bucket_off, const long long* __restrict__ bkt,
    const unsigned* __restrict__ hb, float* __restrict__ neigh)
{
    __shared__ __align__(16) float acc[BROWS * H];   // 64 KB
    const int t = threadIdx.x;
    const int b = blockIdx.x;
    for (int i = t * 4; i < BROWS * H; i += SPMM_TPB * 4)
        *(float4*)&acc[i] = make_float4(0.f, 0.f, 0.f, 0.f);
    __syncthreads();

    const int lane = t & 63;
    const int w    = t >> 6;                  // wave id 0..7
    const int start = bucket_off[b];
    const int end   = bucket_off[b + 1];
    const int cnt   = end - start;
    const int per   = (cnt + 7) >> 3;
    const int e0 = start + w * per;
    const int e1 = min(e0 + per, end);

    for (int e = e0; e < e1; e += 8) {
        int m = min(8, e1 - e);
        unsigned gv[8]; float vv[8]; int lr[8];
        #pragma unroll
        for (int k = 0; k < 8; k++) {
            if (k < m) {
                long long ed = bkt[e + k];
                unsigned w0 = (unsigned)ed;
                vv[k] = __int_as_float((int)(ed >> 32));
                lr[k] = (int)(w0 >> 24);
                gv[k] = hb[(size_t)(w0 & 0xFFFFFFu) * 64 + lane];
            }
        }
        #pragma unroll
        for (int k = 0; k < 8; k++) {
            if (k < m) {
                float lo = __uint_as_float(gv[k] << 16) * vv[k];
                float hi = __uint_as_float(gv[k] & 0xFFFF0000u) * vv[k];
                atomicAdd(&acc[lr[k] * H + 2 * lane], lo);
                atomicAdd(&acc[lr[k] * H + 2 * lane + 1], hi);
            }
        }
    }
    __syncthreads();
    const int row0  = b * BROWS;
    const int nrows = min(BROWS, N_NODES - row0);
    for (int i = t; i < nrows * (H / 4); i += SPMM_TPB) {
        int r = i >> 5, c = (i & 31) * 4;
        *(float4*)(neigh + (size_t)(row0 + r) * H + c) = *(const float4*)&acc[r * H + c];
    }
}

// f32-gather variant (tier B: no hb buffer)
__global__ __launch_bounds__(SPMM_TPB, 1) void k_spmm_bucket_f32(
    const int* __restrict__ bucket_off, const long long* __restrict__ bkt,
    const float* __restrict__ h, float* __restrict__ neigh)
{
    __shared__ __align__(16) float acc[BROWS * H];
    const int t = threadIdx.x;
    const int b = blockIdx.x;
    for (int i = t * 4; i < BROWS * H; i += SPMM_TPB * 4)
        *(float4*)&acc[i] = make_float4(0.f, 0.f, 0.f, 0.f);
    __syncthreads();

    const int lane = t & 63;
    const int w    = t >> 6;
    const int start = bucket_off[b];
    const int end   = bucket_off[b + 1];
    const int cnt   = end - start;
    const int per   = (cnt + 7) >> 3;
    const int e0 = start + w * per;
    const int e1 = min(e0 + per, end);

    for (int e = e0; e < e1; e += 8) {
        int m = min(8, e1 - e);
        float2 gv[8]; float vv[8]; int lr[8];
        #pragma unroll
        for (int k = 0; k < 8; k++) {
            if (k < m) {
                long long ed = bkt[e + k];
                unsigned w0 = (unsigned)ed;
                vv[k] = __int_as_float((int)(ed >> 32));
                lr[k] = (int)(w0 >> 24);
                gv[k] = *((const float2*)(h + (size_t)(w0 & 0xFFFFFFu) * H) + lane);
            }
        }
        #pragma unroll
        for (int k = 0; k < 8; k++) {
            if (k < m) {
                atomicAdd(&acc[lr[k] * H + 2 * lane],     gv[k].x * vv[k]);
                atomicAdd(&acc[lr[k] * H + 2 * lane + 1], gv[k].y * vv[k]);
            }
        }
    }
    __syncthreads();
    const int row0  = b * BROWS;
    const int nrows = min(BROWS, N_NODES - row0);
    for (int i = t; i < nrows * (H / 4); i += SPMM_TPB) {
        int r = i >> 5, c = (i & 31) * 4;
        *(float4*)(neigh + (size_t)(row0 + r) * H + c) = *(const float4*)&acc[r * H + c];
    }
}

// Tier C fallback: atomic SpMM (only if ws is tiny; never expected)
__global__ __launch_bounds__(TPB) void k_spmm_atomic(
    const int* __restrict__ erow, const int* __restrict__ ecol,
    const float* __restrict__ eval, const float* __restrict__ h,
    float* __restrict__ neigh)
{
    unsigned int gid = blockIdx.x * TPB + threadIdx.x;
    int e = (int)(gid >> 5);
    if (e >= N_EDGES) return;
    int c = ((int)gid & 31) * 4;
    int col = ecol[e];
    int row = erow[e];
    float v = eval[e];
    const float4 hv = *(const float4*)(h + (size_t)col * H + c);
    float* dst = neigh + (size_t)row * H + c;
    unsafeAtomicAdd(dst + 0, v * hv.x);
    unsafeAtomicAdd(dst + 1, v * hv.y);
    unsafeAtomicAdd(dst + 2, v * hv.z);
    unsafeAtomicAdd(dst + 3, v * hv.w);
}

// ---------------------------------------------------------------------------
// K3: dense layer update: h += relu(h@Ws + bs + neigh@Wn + bn)  (in place)
// 4x4 register blocking, float4 LDS reads, optional fused bf16 pack.
// ---------------------------------------------------------------------------
__global__ __launch_bounds__(TPB) void k_layer_dense(
    const float* __restrict__ neigh,
    const float* __restrict__ Wself, const float* __restrict__ bself,
    const float* __restrict__ Wneigh, const float* __restrict__ bneigh,
    float* __restrict__ h, unsigned* __restrict__ hb)
{
    __shared__ float h_lds[NPB][H];
    __shared__ float n_lds[NPB][H];
    const int tid  = threadIdx.x;
    const int base = blockIdx.x * NPB;

    for (int idx = tid; idx < NPB * H / 4; idx += TPB) {
        int r = idx >> 5, c = (idx & 31) * 4;
        *(float4*)&h_lds[r][c] = *(const float4*)(h + (size_t)(base + r) * H + c);
        *(float4*)&n_lds[r][c] = *(const float4*)(neigh + (size_t)(base + r) * H + c);
    }
    __syncthreads();

    const int c0 = (tid & 31) * 4;
    const int r0 = (tid >> 5) * 4;

    float acc[4][4];
    #pragma unroll
    for (int i = 0; i < 4; i++)
        #pragma unroll
        for (int j = 0; j < 4; j++) acc[i][j] = 0.f;

    for (int k = 0; k < H; k += 4) {
        float4 a[4], b[4];
        #pragma unroll
        for (int i = 0; i < 4; i++) {
            a[i] = *(const float4*)&h_lds[r0 + i][k];
            b[i] = *(const float4*)&n_lds[r0 + i][k];
        }
        #pragma unroll
        for (int kk = 0; kk < 4; kk++) {
            float4 ws = *(const float4*)(Wself  + (size_t)(k + kk) * H + c0);
            float4 wn = *(const float4*)(Wneigh + (size_t)(k + kk) * H + c0);
            const float* wsf = (const float*)&ws;
            const float* wnf = (const float*)&wn;
            #pragma unroll
            for (int i = 0; i < 4; i++) {
                float av = ((const float*)&a[i])[kk];
                float bv = ((const float*)&b[i])[kk];
                #pragma unroll
                for (int j = 0; j < 4; j++)
                    acc[i][j] += av * wsf[j] + bv * wnf[j];
            }
        }
    }

    float4 bs = *(const float4*)(bself + c0);
    float4 bn = *(const float4*)(bneigh + c0);
    const float* bsf = (const float*)&bs;
    const float* bnf = (const float*)&bn;
    #pragma unroll
    for (int i = 0; i < 4; i++) {
        int node = base + r0 + i;
        float4 out;
        float* of = (float*)&out;
        #pragma unroll
        for (int j = 0; j < 4; j++) {
            float v = fmaxf(acc[i][j] + bsf[j] + bnf[j], 0.f);
            of[j] = h_lds[r0 + i][c0 + j] + v;
        }
        *(float4*)(h + (size_t)node * H + c0) = out;
        if (hb) {
            uint2 p;
            p.x = bf_rne(of[0]) | (bf_rne(of[1]) << 16);
            p.y = bf_rne(of[2]) | (bf_rne(of[3]) << 16);
            *(uint2*)(hb + (size_t)node * 64 + (c0 >> 1)) = p;
        }
    }
}

// ---------------------------------------------------------------------------
// K4: mean/max pool (h >= 0 so int atomicMax and zero identity are valid)
// ---------------------------------------------------------------------------
__global__ __launch_bounds__(TPB) void k_reduce(
    const float* __restrict__ h, float* __restrict__ g)
{
    __shared__ float s_sum[TPB];
    __shared__ float s_max[TPB];
    const int tid = threadIdx.x;
    const int col = tid & 127;
    const int rg  = tid >> 7;

    float sum = 0.f, mx = 0.f;
    for (int row = blockIdx.x * 2 + rg; row < N_NODES; row += gridDim.x * 2) {
        float v = h[(size_t)row * H + col];
        sum += v;
        mx = fmaxf(mx, v);
    }
    s_sum[tid] = sum;
    s_max[tid] = mx;
    __syncthreads();
    if (tid < 128) {
        sum = s_sum[tid] + s_sum[tid + 128];
        mx  = fmaxf(s_max[tid], s_max[tid + 128]);
        unsafeAtomicAdd(&g[col], sum);
        atomicMax((int*)&g[128 + col], __float_as_int(mx));
    }
}

__global__ void k_finalize(float* __restrict__ g)
{
    int t = threadIdx.x;
    if (t < 128) g[t] *= (1.0f / (float)N_NODES);
}

// ---------------------------------------------------------------------------
extern "C" void kernel_launch(void* const* d_in, const int* in_sizes, int n_in,
                              void* d_out, int out_size, void* d_ws, size_t ws_size,
                              hipStream_t stream)
{
    const int*   midx  = (const int*)  d_in[0];
    const int*   widx  = (const int*)  d_in[1];
    const int*   tidx  = (const int*)  d_in[2];
    const float* cont  = (const float*)d_in[3];
    const int*   erow  = (const int*)  d_in[4];
    const int*   ecol  = (const int*)  d_in[5];
    const float* eval  = (const float*)d_in[6];
    const float* memb  = (const float*)d_in[7];
    const float* wemb  = (const float*)d_in[8];
    const float* temb  = (const float*)d_in[9];
    const float* W1    = (const float*)d_in[10];
    const float* b1    = (const float*)d_in[11];
    const float* W2    = (const float*)d_in[12];
    const float* b2    = (const float*)d_in[13];
    const float* Wself = (const float*)d_in[14];
    const float* bself = (const float*)d_in[15];
    const float* Wneigh= (const float*)d_in[16];
    const float* bneigh= (const float*)d_in[17];

    float* g = (float*)d_out;   // [256]
    float* h = g + 256;         // [N, H] lives in d_out

    // ---- workspace layout ----
    const size_t neigh_elems = (size_t)N_NODES * H;        // 25.6 M floats
    const size_t hb_elems    = (size_t)N_NODES * H / 2;    // 12.8 M u32
    const size_t int_elems   = (size_t)(NBUCK + (NBUCK + 1) + NBUCK + 64);

    const size_t tierB_bytes = neigh_elems * 4 + (size_t)N_EDGES * 8 + int_elems * 4;
    const size_t tierA_bytes = tierB_bytes + hb_elems * 4;

    const bool tierA = (ws_size >= tierA_bytes);
    const bool tierB = (ws_size >= tierB_bytes);

    float*     neigh = (float*)d_ws;
    unsigned*  hb    = (unsigned*)(neigh + neigh_elems);
    long long* bkt;
    int*       bhist;
    if (tierA) {
        bkt = (long long*)(hb + hb_elems);
    } else {
        bkt = (long long*)(neigh + neigh_elems);
    }
    bhist = (int*)(bkt + N_EDGES);
    int* bucket_off = bhist + NBUCK;          // NBUCK+1
    int* bucket_cur = bucket_off + NBUCK + 1; // NBUCK

    hipMemsetAsync(d_out, 0, 256 * sizeof(float), stream);

    k_input_mlp<<<N_NODES / NPB, TPB, 0, stream>>>(
        midx, widx, tidx, cont, memb, wemb, temb, W1, b1, W2, b2, h,
        tierA ? hb : nullptr);

    if (tierB) {
        hipMemsetAsync(bhist, 0, NBUCK * sizeof(int), stream);
        k_bucket_hist<<<2048, 256, 0, stream>>>(erow, bhist);
        k_scan_buckets<<<1, 1024, 0, stream>>>(bhist, bucket_off, bucket_cur);
        k_bucket_sort<<<N_SORT_BLOCKS, SORT_TPB, 0, stream>>>(
            erow, ecol, eval, bucket_cur, bkt);

        for (int l = 0; l < 2; l++) {
            if (tierA) {
                k_spmm_bucket_bf16<<<NBUCK, SPMM_TPB, 0, stream>>>(
                    bucket_off, bkt, hb, neigh);
            } else {
                k_spmm_bucket_f32<<<NBUCK, SPMM_TPB, 0, stream>>>(
                    bucket_off, bkt, h, neigh);
            }
            k_layer_dense<<<N_NODES / NPB, TPB, 0, stream>>>(
                neigh, Wself + (size_t)l * H * H, bself + (size_t)l * H,
                Wneigh + (size_t)l * H * H, bneigh + (size_t)l * H, h,
                (tierA && l == 0) ? hb : nullptr);
        }
    } else {
        for (int l = 0; l < 2; l++) {
            hipMemsetAsync(neigh, 0, neigh_elems * sizeof(float), stream);
            unsigned int nthreads = (unsigned int)N_EDGES * 32u;
            k_spmm_atomic<<<nthreads / TPB, TPB, 0, stream>>>(erow, ecol, eval, h, neigh);
            k_layer_dense<<<N_NODES / NPB, TPB, 0, stream>>>(
                neigh, Wself + (size_t)l * H * H, bself + (size_t)l * H,
                Wneigh + (size_t)l * H * H, bneigh + (size_t)l * H, h, nullptr);
        }
    }

    k_reduce<<<2048, TPB, 0, stream>>>(h, g);
    k_finalize<<<1, 128, 0, stream>>>(g);
}

// Round 6
// 1625.205 us; speedup vs baseline: 6.5016x; 6.5016x over previous
//
#include <hip/hip_runtime.h>

#define N_NODES 200000
#define N_EDGES 6400000
#define EMB 16
#define CONT 12
#define H 128
#define IN_DIM 60   // 3*EMB + CONT
#define NPB 32      // nodes per block for dense kernels
#define TPB 256

#define BROWS 128                                    // rows per bucket
#define NBUCK ((N_NODES + BROWS - 1) / BROWS)        // 1563
#define SORT_TILE 16384
#define SORT_TPB 512
#define N_SORT_BLOCKS ((N_EDGES + SORT_TILE - 1) / SORT_TILE)  // 391

// bf16 round-to-nearest-even pack helper (h >= 0, finite)
__device__ __forceinline__ unsigned bf_rne(float f) {
    unsigned u = __float_as_uint(f);
    return (u + 0x7FFFu + ((u >> 16) & 1u)) >> 16;
}

// ---------------------------------------------------------------------------
// K1: fused embedding gather + 2-layer input MLP + optional bf16 pack.
// 4x4 register blocking: FMA-bound, LDS broadcast reads. (proven r4)
// ---------------------------------------------------------------------------
__global__ __launch_bounds__(TPB) void k_input_mlp(
    const int* __restrict__ midx, const int* __restrict__ widx,
    const int* __restrict__ tidx, const float* __restrict__ cont,
    const float* __restrict__ memb, const float* __restrict__ wemb,
    const float* __restrict__ temb,
    const float* __restrict__ W1, const float* __restrict__ b1,
    const float* __restrict__ W2, const float* __restrict__ b2,
    float* __restrict__ h, unsigned* __restrict__ hb)
{
    __shared__ float x_lds[NPB][IN_DIM];
    __shared__ float h0_lds[NPB][H];
    const int tid  = threadIdx.x;
    const int base = blockIdx.x * NPB;

    for (int idx = tid; idx < NPB * IN_DIM; idx += TPB) {
        int n = idx / IN_DIM, k = idx % IN_DIM;
        int node = base + n;
        float v;
        if (k < 16)       v = memb[midx[node] * 16 + k];
        else if (k < 32)  v = wemb[widx[node] * 16 + (k - 16)];
        else if (k < 48)  v = temb[tidx[node] * 16 + (k - 32)];
        else              v = cont[(size_t)node * CONT + (k - 48)];
        x_lds[n][k] = v;
    }
    __syncthreads();

    const int c0 = (tid & 31) * 4;
    const int r0 = (tid >> 5) * 4;

    float acc[4][4];
    #pragma unroll
    for (int i = 0; i < 4; i++)
        #pragma unroll
        for (int j = 0; j < 4; j++) acc[i][j] = 0.f;

    for (int k = 0; k < IN_DIM; k += 4) {
        float4 a[4];
        #pragma unroll
        for (int i = 0; i < 4; i++) a[i] = *(const float4*)&x_lds[r0 + i][k];
        #pragma unroll
        for (int kk = 0; kk < 4; kk++) {
            float4 w = *(const float4*)(W1 + (size_t)(k + kk) * H + c0);
            const float* wf = (const float*)&w;
            #pragma unroll
            for (int i = 0; i < 4; i++) {
                float av = ((const float*)&a[i])[kk];
                #pragma unroll
                for (int j = 0; j < 4; j++)
                    acc[i][j] += av * wf[j];
            }
        }
    }
    {
        float4 bv = *(const float4*)(b1 + c0);
        const float* bf = (const float*)&bv;
        #pragma unroll
        for (int i = 0; i < 4; i++)
            #pragma unroll
            for (int j = 0; j < 4; j++)
                h0_lds[r0 + i][c0 + j] = fmaxf(acc[i][j] + bf[j], 0.f);
    }
    __syncthreads();

    #pragma unroll
    for (int i = 0; i < 4; i++)
        #pragma unroll
        for (int j = 0; j < 4; j++) acc[i][j] = 0.f;

    for (int k = 0; k < H; k += 4) {
        float4 a[4];
        #pragma unroll
        for (int i = 0; i < 4; i++) a[i] = *(const float4*)&h0_lds[r0 + i][k];
        #pragma unroll
        for (int kk = 0; kk < 4; kk++) {
            float4 w = *(const float4*)(W2 + (size_t)(k + kk) * H + c0);
            const float* wf = (const float*)&w;
            #pragma unroll
            for (int i = 0; i < 4; i++) {
                float av = ((const float*)&a[i])[kk];
                #pragma unroll
                for (int j = 0; j < 4; j++)
                    acc[i][j] += av * wf[j];
            }
        }
    }
    {
        float4 bv = *(const float4*)(b2 + c0);
        const float* bf = (const float*)&bv;
        #pragma unroll
        for (int i = 0; i < 4; i++) {
            int node = base + r0 + i;
            float4 out;
            float* of = (float*)&out;
            #pragma unroll
            for (int j = 0; j < 4; j++)
                of[j] = fmaxf(acc[i][j] + bf[j], 0.f);
            *(float4*)(h + (size_t)node * H + c0) = out;
            if (hb) {
                uint2 p;
                p.x = bf_rne(of[0]) | (bf_rne(of[1]) << 16);
                p.y = bf_rne(of[2]) | (bf_rne(of[3]) << 16);
                *(uint2*)(hb + (size_t)node * 64 + (c0 >> 1)) = p;
            }
        }
    }
}

// ---------------------------------------------------------------------------
// CSR build, two-phase write-combined:
//   hist -> scan -> phase1 bucket scatter (tile-segmented) -> phase2 row sort
// Entry format: low24 = col, bits24..31 = row-within-bucket, high32 = val.
// ---------------------------------------------------------------------------
__global__ __launch_bounds__(256) void k_bucket_hist(
    const int* __restrict__ erow, int* __restrict__ bhist)
{
    __shared__ int lh[NBUCK];
    for (int i = threadIdx.x; i < NBUCK; i += 256) lh[i] = 0;
    __syncthreads();
    for (int e = blockIdx.x * 256 + threadIdx.x; e < N_EDGES; e += gridDim.x * 256)
        atomicAdd(&lh[erow[e] >> 7], 1);
    __syncthreads();
    for (int i = threadIdx.x; i < NBUCK; i += 256) {
        int v = lh[i];
        if (v) atomicAdd(&bhist[i], v);
    }
}

__global__ __launch_bounds__(1024) void k_scan_buckets(
    const int* __restrict__ bhist, int* __restrict__ bucket_off,
    int* __restrict__ bucket_cur, int* __restrict__ row_ptr)
{
    __shared__ int s[1024];
    int t = threadIdx.x;
    int i0 = t * 2, i1 = t * 2 + 1;
    int v0 = (i0 < NBUCK) ? bhist[i0] : 0;
    int v1 = (i1 < NBUCK) ? bhist[i1] : 0;
    s[t] = v0 + v1;
    __syncthreads();
    for (int off = 1; off < 1024; off <<= 1) {
        int u = (t >= off) ? s[t - off] : 0;
        __syncthreads();
        s[t] += u;
        __syncthreads();
    }
    int base = (t > 0) ? s[t - 1] : 0;
    if (i0 < NBUCK) { bucket_off[i0] = base;      bucket_cur[i0] = base; }
    if (i1 < NBUCK) { bucket_off[i1] = base + v0; bucket_cur[i1] = base + v0; }
    if (t == 1023) {
        bucket_off[NBUCK] = s[1023];      // == N_EDGES
        row_ptr[N_NODES]  = s[1023];
    }
}

// phase 1: scatter to bucket granularity. Each tile reserves contiguous
// per-bucket segments so a segment's writes come from one block (one XCD):
// L2 write-combines lines (r5 evidence: exact-row scatter had 7.7x write amp).
__global__ __launch_bounds__(SORT_TPB) void k_bucket_sort(
    const int* __restrict__ erow, const int* __restrict__ ecol,
    const float* __restrict__ eval, int* __restrict__ bucket_cur,
    long long* __restrict__ bkt)
{
    __shared__ int hist[NBUCK];
    __shared__ int gbase[NBUCK];
    __shared__ int fcur[NBUCK];
    const int t = threadIdx.x;
    const int tile0 = blockIdx.x * SORT_TILE;
    const int nE = min(SORT_TILE, N_EDGES - tile0);

    for (int i = t; i < NBUCK; i += SORT_TPB) { hist[i] = 0; fcur[i] = 0; }
    __syncthreads();
    for (int i = t; i < nE; i += SORT_TPB)
        atomicAdd(&hist[erow[tile0 + i] >> 7], 1);
    __syncthreads();
    for (int i = t; i < NBUCK; i += SORT_TPB) {
        int c = hist[i];
        if (c) gbase[i] = atomicAdd(&bucket_cur[i], c);
    }
    __syncthreads();
    for (int i = t; i < nE; i += SORT_TPB) {
        int r = erow[tile0 + i];
        int b = r >> 7;
        int off = atomicAdd(&fcur[b], 1);
        unsigned w0 = (unsigned)ecol[tile0 + i] | ((unsigned)(r & 127) << 24);
        unsigned w1 = (unsigned)__float_as_int(eval[tile0 + i]);
        bkt[gbase[b] + off] = (long long)(((unsigned long long)w1 << 32) | w0);
    }
}

// phase 2: one block per bucket. Count rows -> scan -> scatter to exact-row
// CSR order within the bucket's own window (single-block L2 locality).
__global__ __launch_bounds__(512) void k_row_sort(
    const int* __restrict__ bucket_off, const long long* __restrict__ bkt,
    long long* __restrict__ csr, int* __restrict__ row_ptr)
{
    __shared__ int cnt[BROWS];
    __shared__ int cur[BROWS];
    const int t = threadIdx.x;
    const int b = blockIdx.x;
    const int start = bucket_off[b];
    const int end   = bucket_off[b + 1];
    const int n = end - start;

    if (t < BROWS) cnt[t] = 0;
    __syncthreads();
    for (int i = t; i < n; i += 512) {
        int w0 = ((const int2*)bkt)[start + i].x;
        atomicAdd(&cnt[(unsigned)w0 >> 24], 1);
    }
    __syncthreads();
    if (t < BROWS) cur[t] = cnt[t];
    __syncthreads();
    for (int off = 1; off < BROWS; off <<= 1) {
        int v = 0;
        if (t < BROWS && t >= off) v = cur[t - off];
        __syncthreads();
        if (t < BROWS) cur[t] += v;
        __syncthreads();
    }
    if (t < BROWS) {
        int excl = cur[t] - cnt[t];          // exclusive scan
        cur[t] = excl;                       // becomes cursor
        int row = b * BROWS + t;
        if (row < N_NODES) row_ptr[row] = start + excl;
    }
    __syncthreads();
    for (int i = t; i < n; i += 512) {
        long long ed = bkt[start + i];
        int lr = (int)((unsigned)ed >> 24);
        int p = atomicAdd(&cur[lr], 1);
        csr[start + p] = ed;
    }
}

// ---------------------------------------------------------------------------
// K2: CSR SpMM — one wave per row, register accumulation, bf16 gathers,
// 8 edges in flight per wave (r4 structure, deeper unroll).
// ---------------------------------------------------------------------------
__global__ __launch_bounds__(TPB) void k_spmm_csr_bf16(
    const int* __restrict__ row_ptr, const int2* __restrict__ csr,
    const unsigned* __restrict__ hb, float* __restrict__ neigh)
{
    int row = (int)((blockIdx.x * TPB + threadIdx.x) >> 6);
    if (row >= N_NODES) return;
    int lane = threadIdx.x & 63;

    int e   = row_ptr[row];
    int end = row_ptr[row + 1];

    float ax = 0.f, ay = 0.f;
    for (; e + 8 <= end; e += 8) {
        int2 c[8];
        #pragma unroll
        for (int k = 0; k < 8; k++) c[k] = csr[e + k];
        unsigned gv[8];
        #pragma unroll
        for (int k = 0; k < 8; k++)
            gv[k] = hb[(size_t)((unsigned)c[k].x & 0xFFFFFFu) * 64 + lane];
        #pragma unroll
        for (int k = 0; k < 8; k++) {
            float v = __int_as_float(c[k].y);
            ax += v * __uint_as_float(gv[k] << 16);
            ay += v * __uint_as_float(gv[k] & 0xFFFF0000u);
        }
    }
    for (; e < end; e++) {
        int2 c = csr[e];
        unsigned g = hb[(size_t)((unsigned)c.x & 0xFFFFFFu) * 64 + lane];
        float v = __int_as_float(c.y);
        ax += v * __uint_as_float(g << 16);
        ay += v * __uint_as_float(g & 0xFFFF0000u);
    }
    *((float2*)(neigh + (size_t)row * H) + lane) = make_float2(ax, ay);
}

// f32-gather variant (tier B: no hb buffer)
__global__ __launch_bounds__(TPB) void k_spmm_csr_f32(
    const int* __restrict__ row_ptr, const int2* __restrict__ csr,
    const float* __restrict__ h, float* __restrict__ neigh)
{
    int row = (int)((blockIdx.x * TPB + threadIdx.x) >> 6);
    if (row >= N_NODES) return;
    int lane = threadIdx.x & 63;
    int e   = row_ptr[row];
    int end = row_ptr[row + 1];
    float ax = 0.f, ay = 0.f;
    for (; e + 4 <= end; e += 4) {
        int2 c[4];
        #pragma unroll
        for (int k = 0; k < 4; k++) c[k] = csr[e + k];
        float2 gv[4];
        #pragma unroll
        for (int k = 0; k < 4; k++)
            gv[k] = *((const float2*)(h + (size_t)((unsigned)c[k].x & 0xFFFFFFu) * H) + lane);
        #pragma unroll
        for (int k = 0; k < 4; k++) {
            float v = __int_as_float(c[k].y);
            ax += v * gv[k].x;
            ay += v * gv[k].y;
        }
    }
    for (; e < end; e++) {
        int2 c = csr[e];
        float2 gv = *((const float2*)(h + (size_t)((unsigned)c.x & 0xFFFFFFu) * H) + lane);
        float v = __int_as_float(c.y);
        ax += v * gv.x;
        ay += v * gv.y;
    }
    *((float2*)(neigh + (size_t)row * H) + lane) = make_float2(ax, ay);
}

// Tier C fallback: atomic SpMM
__global__ __launch_bounds__(TPB) void k_spmm_atomic(
    const int* __restrict__ erow, const int* __restrict__ ecol,
    const float* __restrict__ eval, const float* __restrict__ h,
    float* __restrict__ neigh)
{
    unsigned int gid = blockIdx.x * TPB + threadIdx.x;
    int e = (int)(gid >> 5);
    if (e >= N_EDGES) return;
    int c = ((int)gid & 31) * 4;
    int col = ecol[e];
    int row = erow[e];
    float v = eval[e];
    const float4 hv = *(const float4*)(h + (size_t)col * H + c);
    float* dst = neigh + (size_t)row * H + c;
    unsafeAtomicAdd(dst + 0, v * hv.x);
    unsafeAtomicAdd(dst + 1, v * hv.y);
    unsafeAtomicAdd(dst + 2, v * hv.z);
    unsafeAtomicAdd(dst + 3, v * hv.w);
}

// ---------------------------------------------------------------------------
// K3: dense layer update: h += relu(h@Ws + bs + neigh@Wn + bn)  (in place)
// 4x4 register blocking + optional fused bf16 pack + (l==1) fused mean/max
// pooling epilogue (saves the separate 102-MB reduce pass).
// ---------------------------------------------------------------------------
__global__ __launch_bounds__(TPB) void k_layer_dense(
    const float* __restrict__ neigh,
    const float* __restrict__ Wself, const float* __restrict__ bself,
    const float* __restrict__ Wneigh, const float* __restrict__ bneigh,
    float* __restrict__ h, unsigned* __restrict__ hb,
    float* __restrict__ gout, int do_pool)
{
    __shared__ float h_lds[NPB][H];
    __shared__ float n_lds[NPB][H];
    __shared__ float psum[8][H];
    __shared__ float pmax[8][H];
    const int tid  = threadIdx.x;
    const int base = blockIdx.x * NPB;

    for (int idx = tid; idx < NPB * H / 4; idx += TPB) {
        int r = idx >> 5, c = (idx & 31) * 4;
        *(float4*)&h_lds[r][c] = *(const float4*)(h + (size_t)(base + r) * H + c);
        *(float4*)&n_lds[r][c] = *(const float4*)(neigh + (size_t)(base + r) * H + c);
    }
    __syncthreads();

    const int c0 = (tid & 31) * 4;
    const int r0 = (tid >> 5) * 4;
    const int grp = tid >> 5;

    float acc[4][4];
    #pragma unroll
    for (int i = 0; i < 4; i++)
        #pragma unroll
        for (int j = 0; j < 4; j++) acc[i][j] = 0.f;

    for (int k = 0; k < H; k += 4) {
        float4 a[4], b[4];
        #pragma unroll
        for (int i = 0; i < 4; i++) {
            a[i] = *(const float4*)&h_lds[r0 + i][k];
            b[i] = *(const float4*)&n_lds[r0 + i][k];
        }
        #pragma unroll
        for (int kk = 0; kk < 4; kk++) {
            float4 ws = *(const float4*)(Wself  + (size_t)(k + kk) * H + c0);
            float4 wn = *(const float4*)(Wneigh + (size_t)(k + kk) * H + c0);
            const float* wsf = (const float*)&ws;
            const float* wnf = (const float*)&wn;
            #pragma unroll
            for (int i = 0; i < 4; i++) {
                float av = ((const float*)&a[i])[kk];
                float bv = ((const float*)&b[i])[kk];
                #pragma unroll
                for (int j = 0; j < 4; j++)
                    acc[i][j] += av * wsf[j] + bv * wnf[j];
            }
        }
    }

    float4 bs = *(const float4*)(bself + c0);
    float4 bn = *(const float4*)(bneigh + c0);
    const float* bsf = (const float*)&bs;
    const float* bnf = (const float*)&bn;
    float csum[4] = {0.f, 0.f, 0.f, 0.f};
    float cmax[4] = {0.f, 0.f, 0.f, 0.f};
    #pragma unroll
    for (int i = 0; i < 4; i++) {
        int node = base + r0 + i;
        float4 out;
        float* of = (float*)&out;
        #pragma unroll
        for (int j = 0; j < 4; j++) {
            float v = fmaxf(acc[i][j] + bsf[j] + bnf[j], 0.f);
            of[j] = h_lds[r0 + i][c0 + j] + v;
            csum[j] += of[j];
            cmax[j] = fmaxf(cmax[j], of[j]);
        }
        *(float4*)(h + (size_t)node * H + c0) = out;
        if (hb) {
            uint2 p;
            p.x = bf_rne(of[0]) | (bf_rne(of[1]) << 16);
            p.y = bf_rne(of[2]) | (bf_rne(of[3]) << 16);
            *(uint2*)(hb + (size_t)node * 64 + (c0 >> 1)) = p;
        }
    }

    if (do_pool) {
        #pragma unroll
        for (int j = 0; j < 4; j++) {
            psum[grp][c0 + j] = csum[j];
            pmax[grp][c0 + j] = cmax[j];
        }
        __syncthreads();
        if (tid < H) {
            float s = 0.f, m = 0.f;
            #pragma unroll
            for (int gix = 0; gix < 8; gix++) {
                s += psum[gix][tid];
                m = fmaxf(m, pmax[gix][tid]);
            }
            unsafeAtomicAdd(&gout[tid], s);
            atomicMax((int*)&gout[H + tid], __float_as_int(m));
        }
    }
}

__global__ void k_finalize(float* __restrict__ g)
{
    int t = threadIdx.x;
    if (t < 128) g[t] *= (1.0f / (float)N_NODES);
}

// ---------------------------------------------------------------------------
extern "C" void kernel_launch(void* const* d_in, const int* in_sizes, int n_in,
                              void* d_out, int out_size, void* d_ws, size_t ws_size,
                              hipStream_t stream)
{
    const int*   midx  = (const int*)  d_in[0];
    const int*   widx  = (const int*)  d_in[1];
    const int*   tidx  = (const int*)  d_in[2];
    const float* cont  = (const float*)d_in[3];
    const int*   erow  = (const int*)  d_in[4];
    const int*   ecol  = (const int*)  d_in[5];
    const float* eval  = (const float*)d_in[6];
    const float* memb  = (const float*)d_in[7];
    const float* wemb  = (const float*)d_in[8];
    const float* temb  = (const float*)d_in[9];
    const float* W1    = (const float*)d_in[10];
    const float* b1    = (const float*)d_in[11];
    const float* W2    = (const float*)d_in[12];
    const float* b2    = (const float*)d_in[13];
    const float* Wself = (const float*)d_in[14];
    const float* bself = (const float*)d_in[15];
    const float* Wneigh= (const float*)d_in[16];
    const float* bneigh= (const float*)d_in[17];

    float* g = (float*)d_out;   // [256]
    float* h = g + 256;         // [N, H] lives in d_out

    // ---- workspace layout ----
    // neigh: 102.4 MB.  bkt (phase-1 buffer, 51.2 MB) ALIASES neigh: it is
    // fully consumed by k_row_sort before the first SpMM writes neigh.
    const size_t neigh_elems = (size_t)N_NODES * H;      // 25.6 M floats
    const size_t hb_elems    = (size_t)N_NODES * H / 2;  // 12.8 M u32

    float*     neigh = (float*)d_ws;
    long long* bkt   = (long long*)d_ws;                 // alias (see above)

    // tier A layout (with hb)
    unsigned*  hb    = (unsigned*)(neigh + neigh_elems);
    long long* csrA  = (long long*)(hb + hb_elems);
    // tier B layout (no hb)
    long long* csrB  = (long long*)(neigh + neigh_elems);

    const size_t tail_ints   = (size_t)(N_NODES + 2) + NBUCK + (NBUCK + 1) + NBUCK + 16;
    const size_t tierB_bytes = neigh_elems * 4 + (size_t)N_EDGES * 8 + tail_ints * 4;
    const size_t tierA_bytes = tierB_bytes + hb_elems * 4;
    const bool tierA = (ws_size >= tierA_bytes);
    const bool tierB = (ws_size >= tierB_bytes);

    long long* csr = tierA ? csrA : csrB;
    int* row_ptr    = (int*)(csr + N_EDGES);   // N+2
    int* bhist      = row_ptr + N_NODES + 2;   // NBUCK
    int* bucket_off = bhist + NBUCK;           // NBUCK+1
    int* bucket_cur = bucket_off + NBUCK + 1;  // NBUCK

    hipMemsetAsync(d_out, 0, 256 * sizeof(float), stream);

    k_input_mlp<<<N_NODES / NPB, TPB, 0, stream>>>(
        midx, widx, tidx, cont, memb, wemb, temb, W1, b1, W2, b2, h,
        tierA ? hb : nullptr);

    if (tierB) {
        hipMemsetAsync(bhist, 0, NBUCK * sizeof(int), stream);
        k_bucket_hist<<<2048, 256, 0, stream>>>(erow, bhist);
        k_scan_buckets<<<1, 1024, 0, stream>>>(bhist, bucket_off, bucket_cur, row_ptr);
        k_bucket_sort<<<N_SORT_BLOCKS, SORT_TPB, 0, stream>>>(
            erow, ecol, eval, bucket_cur, bkt);
        k_row_sort<<<NBUCK, 512, 0, stream>>>(bucket_off, bkt, csr, row_ptr);

        for (int l = 0; l < 2; l++) {
            if (tierA) {
                k_spmm_csr_bf16<<<(N_NODES * 64 + TPB - 1) / TPB, TPB, 0, stream>>>(
                    row_ptr, (const int2*)csr, hb, neigh);
            } else {
                k_spmm_csr_f32<<<(N_NODES * 64 + TPB - 1) / TPB, TPB, 0, stream>>>(
                    row_ptr, (const int2*)csr, h, neigh);
            }
            k_layer_dense<<<N_NODES / NPB, TPB, 0, stream>>>(
                neigh, Wself + (size_t)l * H * H, bself + (size_t)l * H,
                Wneigh + (size_t)l * H * H, bneigh + (size_t)l * H, h,
                (tierA && l == 0) ? hb : nullptr, g, (l == 1) ? 1 : 0);
        }
    } else {
        for (int l = 0; l < 2; l++) {
            hipMemsetAsync(neigh, 0, neigh_elems * sizeof(float), stream);
            unsigned int nthreads = (unsigned int)N_EDGES * 32u;
            k_spmm_atomic<<<nthreads / TPB, TPB, 0, stream>>>(erow, ecol, eval, h, neigh);
            k_layer_dense<<<N_NODES / NPB, TPB, 0, stream>>>(
                neigh, Wself + (size_t)l * H * H, bself + (size_t)l * H,
                Wneigh + (size_t)l * H * H, bneigh + (size_t)l * H, h,
                nullptr, g, (l == 1) ? 1 : 0);
        }
    }

    k_finalize<<<1, 128, 0, stream>>>(g);
}